// Round 2
// baseline (378.779 us; speedup 1.0000x reference)
//
#include <hip/hip_runtime.h>

static constexpr int N = 4096;
static constexpr int D = 8192;
static constexpr int BLOCK = 256;
// per thread: D/4/BLOCK = 8 float4 of embeddings, N/4/BLOCK = 4 int4 of labels

// Completion counter for the fused final reduction. Lives in module .data —
// the harness's workspace poison fills never touch it; the last block resets
// it to 0 so every graph replay starts from a clean state.
__device__ unsigned int g_done = 0;

__global__ __launch_bounds__(BLOCK) void supcon_rows(
    const float* __restrict__ emb,
    const int* __restrict__ labels,
    float* __restrict__ row_out,
    float* __restrict__ out)
{
    const int row = blockIdx.x;
    const int tid = threadIdx.x;
    const int lab_i = labels[row];                       // wave-uniform, s_load-able
    const float4* rowp = reinterpret_cast<const float4*>(emb + (size_t)row * D);
    const int4* labp = reinterpret_cast<const int4*>(labels);

    // Issue ALL global loads up front: 12 loads in flight per wave (max MLP).
    float4 v[8];
    #pragma unroll
    for (int it = 0; it < 8; ++it)
        v[it] = rowp[tid + it * BLOCK];
    int4 lj[4];
    #pragma unroll
    for (int it = 0; it < 4; ++it)
        lj[it] = labp[tid + it * BLOCK];

    float denom = 0.f, ssum = 0.f, diag = 0.f, fcnt = 0.f;

    // First half: j in [0, N) -> denom + masked B-sum + count + diagonal
    #pragma unroll
    for (int it = 0; it < 4; ++it) {
        const int j0 = (tid + it * BLOCK) * 4;
        float xs[4] = {v[it].x, v[it].y, v[it].z, v[it].w};
        int   ls[4] = {lj[it].x, lj[it].y, lj[it].z, lj[it].w};
        #pragma unroll
        for (int k = 0; k < 4; ++k) {
            float a = __expf(xs[k] * xs[k] * 0.1f);
            denom += a;
            float b = __expf(a * 0.1f);                  // unconditional: no divergence
            bool match = (ls[k] == lab_i) && (j0 + k != row);
            ssum += match ? b : 0.f;
            fcnt += match ? 1.f : 0.f;
            diag += (j0 + k == row) ? a : 0.f;           // exactly one lane/block
        }
    }
    // Second half: j in [N, D) -> denom only
    #pragma unroll
    for (int it = 4; it < 8; ++it) {
        float xs[4] = {v[it].x, v[it].y, v[it].z, v[it].w};
        #pragma unroll
        for (int k = 0; k < 4; ++k)
            denom += __expf(xs[k] * xs[k] * 0.1f);
    }

    // wave-64 shuffle reduction
    #pragma unroll
    for (int off = 32; off > 0; off >>= 1) {
        denom += __shfl_down(denom, off);
        ssum  += __shfl_down(ssum,  off);
        diag  += __shfl_down(diag,  off);
        fcnt  += __shfl_down(fcnt,  off);
    }

    __shared__ float s_red[4][4];
    __shared__ float sb[16];
    __shared__ bool  is_last;
    const int wave = tid >> 6;
    if ((tid & 63) == 0) {
        s_red[0][wave] = denom;
        s_red[1][wave] = ssum;
        s_red[2][wave] = diag;
        s_red[3][wave] = fcnt;
    }
    __syncthreads();
    if (tid == 0) {
        float dn = 0.f, sv = 0.f, dg = 0.f, c = 0.f;
        #pragma unroll
        for (int w = 0; w < 4; ++w) {
            dn += s_red[0][w]; sv += s_red[1][w]; dg += s_red[2][w]; c += s_red[3][w];
        }
        dn -= dg;   // denom_i = sum_d A[i,d] - A[i,i]
        row_out[row] = __logf(sv) - __logf(dn) - __logf(c);
        // Publish this row, then find out if we're the last block done.
        __threadfence();                                  // row write visible device-wide
        unsigned int old = atomicAdd(&g_done, 1u);
        is_last = (old == (unsigned)(N - 1));
    }
    __syncthreads();
    if (!is_last) return;

    // ---- Last block: fused final reduction over all 4096 row values. ----
    // Emulates the old 1024-thread reduce_rows EXACTLY (same operands, same
    // addition order): thread tid carries virtual threads tid+256p, p=0..3.
    __threadfence();                                      // acquire: see all row writes
    const float4* rv = reinterpret_cast<const float4*>(row_out);
    float s[4];
    #pragma unroll
    for (int p = 0; p < 4; ++p) {
        float4 x = rv[tid + 256 * p];
        s[p] = x.x + x.y + x.z + x.w;
    }
    #pragma unroll
    for (int off = 32; off > 0; off >>= 1) {
        #pragma unroll
        for (int p = 0; p < 4; ++p)
            s[p] += __shfl_down(s[p], off);
    }
    // Virtual wave of (tid+256p) is (tid>>6) + 4p -> same sb slots as before.
    if ((tid & 63) == 0) {
        #pragma unroll
        for (int p = 0; p < 4; ++p)
            sb[(tid >> 6) + 4 * p] = s[p];
    }
    __syncthreads();
    if (tid == 0) {
        float t = 0.f;
        #pragma unroll
        for (int w = 0; w < 16; ++w) t += sb[w];          // identical w-order
        *out = t;
        g_done = 0;                                       // self-reset for next replay
    }
}

extern "C" void kernel_launch(void* const* d_in, const int* in_sizes, int n_in,
                              void* d_out, int out_size, void* d_ws, size_t ws_size,
                              hipStream_t stream) {
    const float* emb  = (const float*)d_in[0];
    const int* labels = (const int*)d_in[1];
    float* out        = (float*)d_out;
    float* row_vals   = (float*)d_ws;   // 4096 floats = 16 KB scratch

    supcon_rows<<<dim3(N), dim3(BLOCK), 0, stream>>>(emb, labels, row_vals, out);
}

// Round 3
// 188.190 us; speedup vs baseline: 2.0127x; 2.0127x over previous
//
#include <hip/hip_runtime.h>

static constexpr int N = 4096;
static constexpr int D = 8192;
static constexpr int BLOCK = 256;
// Per thread: row = 8 float4. First half (j<N: mask/label math) lives in VGPRs,
// second half (denom-only) is staged global->LDS via async DMA (zero payload VGPRs).

__global__ __launch_bounds__(BLOCK) void supcon_rows(
    const float* __restrict__ emb,
    const int* __restrict__ labels,
    float* __restrict__ row_out)
{
    const int row  = blockIdx.x;
    const int tid  = threadIdx.x;
    const int wave = tid >> 6;          // wave-uniform
    const int lane = tid & 63;
    const int lab_i = labels[row];      // wave-uniform, s_load-able
    const float4* rowp = reinterpret_cast<const float4*>(emb + (size_t)row * D);
    const int4* labp = reinterpret_cast<const int4*>(labels);

    // Per-wave staging region: [wave][issue][lane] float4 = 16 KB total.
    // global_load_lds writes wave-uniform base + lane*16 (m104) -> layout must
    // be linear in lane exactly like this.
    __shared__ float4 s_stage[4][4][64];
    __shared__ float  s_red[4][4];

    // 1) Register loads: first half of row + labels (8 x 16B in flight).
    float4 v[4];
    #pragma unroll
    for (int it = 0; it < 4; ++it)
        v[it] = rowp[tid + it * BLOCK];
    int4 lj[4];
    #pragma unroll
    for (int it = 0; it < 4; ++it)
        lj[it] = labp[tid + it * BLOCK];

    // 2) Async-stage second half of row into LDS: 4 issues/wave, 16B/lane each.
    //    No VGPR payload, no barrier needed (each wave reads only its region).
    #pragma unroll
    for (int it = 0; it < 4; ++it) {
        const float4* g = rowp + (tid + (4 + it) * BLOCK);
        __builtin_amdgcn_global_load_lds(
            (const __attribute__((address_space(1))) void*)g,
            (__attribute__((address_space(3))) void*)&s_stage[wave][it][0],
            16, 0, 0);
    }

    float denom = 0.f, ssum = 0.f, diag = 0.f, fcnt = 0.f;

    // 3) First half: j in [0, N) -> denom + masked B-sum + count + diagonal.
    //    (Identical code/order to the verified round-0 kernel.)
    #pragma unroll
    for (int it = 0; it < 4; ++it) {
        const int j0 = (tid + it * BLOCK) * 4;
        float xs[4] = {v[it].x, v[it].y, v[it].z, v[it].w};
        int   ls[4] = {lj[it].x, lj[it].y, lj[it].z, lj[it].w};
        #pragma unroll
        for (int k = 0; k < 4; ++k) {
            float a = __expf(xs[k] * xs[k] * 0.1f);
            denom += a;
            float b = __expf(a * 0.1f);                  // unconditional: no divergence
            bool match = (ls[k] == lab_i) && (j0 + k != row);
            ssum += match ? b : 0.f;
            fcnt += match ? 1.f : 0.f;
            diag += (j0 + k == row) ? a : 0.f;           // exactly one lane/block
        }
    }

    // 4) Drain this wave's async stages, then fence the scheduler so the LDS
    //    reads below cannot be hoisted above the waitcnt (rule #18).
    asm volatile("s_waitcnt vmcnt(0)" ::: "memory");
    __builtin_amdgcn_sched_barrier(0);

    // 5) Second half: j in [N, D) -> denom only. Same values, same order as
    //    round-0's it=4..7 loop (s_stage[wave][it][lane] == old v[4+it]).
    #pragma unroll
    for (int it = 0; it < 4; ++it) {
        float4 x = s_stage[wave][it][lane];
        float xs[4] = {x.x, x.y, x.z, x.w};
        #pragma unroll
        for (int k = 0; k < 4; ++k)
            denom += __expf(xs[k] * xs[k] * 0.1f);
    }

    // 6) wave-64 shuffle reduction (identical to round-0)
    #pragma unroll
    for (int off = 32; off > 0; off >>= 1) {
        denom += __shfl_down(denom, off);
        ssum  += __shfl_down(ssum,  off);
        diag  += __shfl_down(diag,  off);
        fcnt  += __shfl_down(fcnt,  off);
    }

    if ((tid & 63) == 0) {
        s_red[0][wave] = denom;
        s_red[1][wave] = ssum;
        s_red[2][wave] = diag;
        s_red[3][wave] = fcnt;
    }
    __syncthreads();
    if (tid == 0) {
        float dn = 0.f, sv = 0.f, dg = 0.f, c = 0.f;
        #pragma unroll
        for (int w = 0; w < 4; ++w) {
            dn += s_red[0][w]; sv += s_red[1][w]; dg += s_red[2][w]; c += s_red[3][w];
        }
        dn -= dg;   // denom_i = sum_d A[i,d] - A[i,i]
        row_out[row] = __logf(sv) - __logf(dn) - __logf(c);
    }
}

// 4096 row values -> scalar, one block of 1024 threads (round-0 verbatim)
__global__ __launch_bounds__(1024) void reduce_rows(
    const float* __restrict__ row_vals, float* __restrict__ out)
{
    const int tid = threadIdx.x;
    float4 x = reinterpret_cast<const float4*>(row_vals)[tid];
    float s = x.x + x.y + x.z + x.w;
    #pragma unroll
    for (int off = 32; off > 0; off >>= 1)
        s += __shfl_down(s, off);
    __shared__ float sb[16];
    if ((tid & 63) == 0) sb[tid >> 6] = s;
    __syncthreads();
    if (tid == 0) {
        float t = 0.f;
        #pragma unroll
        for (int w = 0; w < 16; ++w) t += sb[w];
        *out = t;
    }
}

extern "C" void kernel_launch(void* const* d_in, const int* in_sizes, int n_in,
                              void* d_out, int out_size, void* d_ws, size_t ws_size,
                              hipStream_t stream) {
    const float* emb  = (const float*)d_in[0];
    const int* labels = (const int*)d_in[1];
    float* out        = (float*)d_out;
    float* row_vals   = (float*)d_ws;   // 4096 floats = 16 KB scratch

    supcon_rows<<<dim3(N), dim3(BLOCK), 0, stream>>>(emb, labels, row_vals);
    reduce_rows<<<dim3(1), dim3(1024), 0, stream>>>(row_vals, out);
}

// Round 4
// 187.220 us; speedup vs baseline: 2.0232x; 1.0052x over previous
//
#include <hip/hip_runtime.h>

static constexpr int N = 4096;
static constexpr int D = 8192;
static constexpr int BLOCK = 256;
// Per thread: row = 8 float4. First half (j<N: mask/label math) lives in VGPRs,
// second half (denom-only) is staged global->LDS via async DMA (zero payload VGPRs).
// __launch_bounds__(256, 8): 8 waves/EU min -> VGPR capped at 64 -> 8 blocks/CU
// resident (LDS 16.4 KB x 8 = 131 KB < 160 KB). This is the whole point of the
// round: fill the compute-phase MLP holes with other waves' loads.

__global__ __launch_bounds__(BLOCK, 8) void supcon_rows(
    const float* __restrict__ emb,
    const int* __restrict__ labels,
    float* __restrict__ row_out)
{
    const int row  = blockIdx.x;
    const int tid  = threadIdx.x;
    const int wave = tid >> 6;          // wave-uniform
    const int lane = tid & 63;
    const int lab_i = labels[row];      // wave-uniform, s_load-able
    const float4* rowp = reinterpret_cast<const float4*>(emb + (size_t)row * D);
    const int4* labp = reinterpret_cast<const int4*>(labels);

    // Per-wave staging region: [wave][issue][lane] float4 = 16 KB total.
    // global_load_lds writes wave-uniform base + lane*16 (m104) -> layout must
    // be linear in lane exactly like this.
    __shared__ float4 s_stage[4][4][64];
    __shared__ float  s_red[4][4];

    // 1) Register loads: first half of row + labels (8 x 16B in flight).
    float4 v[4];
    #pragma unroll
    for (int it = 0; it < 4; ++it)
        v[it] = rowp[tid + it * BLOCK];
    int4 lj[4];
    #pragma unroll
    for (int it = 0; it < 4; ++it)
        lj[it] = labp[tid + it * BLOCK];

    // 2) Async-stage second half of row into LDS: 4 issues/wave, 16B/lane each.
    //    No VGPR payload, no barrier needed (each wave reads only its region).
    #pragma unroll
    for (int it = 0; it < 4; ++it) {
        const float4* g = rowp + (tid + (4 + it) * BLOCK);
        __builtin_amdgcn_global_load_lds(
            (const __attribute__((address_space(1))) void*)g,
            (__attribute__((address_space(3))) void*)&s_stage[wave][it][0],
            16, 0, 0);
    }

    float denom = 0.f, ssum = 0.f, diag = 0.f, fcnt = 0.f;

    // 3) First half: j in [0, N) -> denom + masked B-sum + count + diagonal.
    //    (Identical code/order to the verified round-0 kernel.)
    #pragma unroll
    for (int it = 0; it < 4; ++it) {
        const int j0 = (tid + it * BLOCK) * 4;
        float xs[4] = {v[it].x, v[it].y, v[it].z, v[it].w};
        int   ls[4] = {lj[it].x, lj[it].y, lj[it].z, lj[it].w};
        #pragma unroll
        for (int k = 0; k < 4; ++k) {
            float a = __expf(xs[k] * xs[k] * 0.1f);
            denom += a;
            float b = __expf(a * 0.1f);                  // unconditional: no divergence
            bool match = (ls[k] == lab_i) && (j0 + k != row);
            ssum += match ? b : 0.f;
            fcnt += match ? 1.f : 0.f;
            diag += (j0 + k == row) ? a : 0.f;           // exactly one lane/block
        }
    }

    // 4) Drain this wave's async stages, then fence the scheduler so the LDS
    //    reads below cannot be hoisted above the waitcnt (rule #18).
    asm volatile("s_waitcnt vmcnt(0)" ::: "memory");
    __builtin_amdgcn_sched_barrier(0);

    // 5) Second half: j in [N, D) -> denom only. Same values, same order as
    //    round-0's it=4..7 loop (s_stage[wave][it][lane] == old v[4+it]).
    #pragma unroll
    for (int it = 0; it < 4; ++it) {
        float4 x = s_stage[wave][it][lane];
        float xs[4] = {x.x, x.y, x.z, x.w};
        #pragma unroll
        for (int k = 0; k < 4; ++k)
            denom += __expf(xs[k] * xs[k] * 0.1f);
    }

    // 6) wave-64 shuffle reduction (identical to round-0)
    #pragma unroll
    for (int off = 32; off > 0; off >>= 1) {
        denom += __shfl_down(denom, off);
        ssum  += __shfl_down(ssum,  off);
        diag  += __shfl_down(diag,  off);
        fcnt  += __shfl_down(fcnt,  off);
    }

    if ((tid & 63) == 0) {
        s_red[0][wave] = denom;
        s_red[1][wave] = ssum;
        s_red[2][wave] = diag;
        s_red[3][wave] = fcnt;
    }
    __syncthreads();
    if (tid == 0) {
        float dn = 0.f, sv = 0.f, dg = 0.f, c = 0.f;
        #pragma unroll
        for (int w = 0; w < 4; ++w) {
            dn += s_red[0][w]; sv += s_red[1][w]; dg += s_red[2][w]; c += s_red[3][w];
        }
        dn -= dg;   // denom_i = sum_d A[i,d] - A[i,i]
        row_out[row] = __logf(sv) - __logf(dn) - __logf(c);
    }
}

// 4096 row values -> scalar, one block of 1024 threads (round-0 verbatim)
__global__ __launch_bounds__(1024) void reduce_rows(
    const float* __restrict__ row_vals, float* __restrict__ out)
{
    const int tid = threadIdx.x;
    float4 x = reinterpret_cast<const float4*>(row_vals)[tid];
    float s = x.x + x.y + x.z + x.w;
    #pragma unroll
    for (int off = 32; off > 0; off >>= 1)
        s += __shfl_down(s, off);
    __shared__ float sb[16];
    if ((tid & 63) == 0) sb[tid >> 6] = s;
    __syncthreads();
    if (tid == 0) {
        float t = 0.f;
        #pragma unroll
        for (int w = 0; w < 16; ++w) t += sb[w];
        *out = t;
    }
}

extern "C" void kernel_launch(void* const* d_in, const int* in_sizes, int n_in,
                              void* d_out, int out_size, void* d_ws, size_t ws_size,
                              hipStream_t stream) {
    const float* emb  = (const float*)d_in[0];
    const int* labels = (const int*)d_in[1];
    float* out        = (float*)d_out;
    float* row_vals   = (float*)d_ws;   // 4096 floats = 16 KB scratch

    supcon_rows<<<dim3(N), dim3(BLOCK), 0, stream>>>(emb, labels, row_vals);
    reduce_rows<<<dim3(1), dim3(1024), 0, stream>>>(row_vals, out);
}